// Round 3
// baseline (2207.474 us; speedup 1.0000x reference)
//
#include <hip/hip_runtime.h>
#include <math.h>

#define N_ 64
#define C_ 384
#define L_ 3136   // 56*56 = 49*64
#define M_ 16
#define D_ 384
#define G_ 8      // l-groups per n (blocks); 49 tiles = 7 + 6*7

// ---------------------------------------------------------------------------
// K1: qs[n][c][m] = (sum_d x[n][m][d] * Wq[c][d] + bq[c]) * (1/sqrt(C))
// (unchanged; bias+scale baked into qs)
// ---------------------------------------------------------------------------
__global__ __launch_bounds__(128) void k1_qproj(const float* __restrict__ x,
                                                const float* __restrict__ Wq,
                                                const float* __restrict__ bq,
                                                float* __restrict__ qs) {
    const int n = blockIdx.x;
    const int c = blockIdx.y * 128 + threadIdx.x;   // 3*128 = 384 exact
    const float4* __restrict__ wrow = (const float4*)(Wq + (size_t)c * D_);
    const float4* __restrict__ xn   = (const float4*)(x + (size_t)n * M_ * D_);
    float acc[M_];
#pragma unroll
    for (int m = 0; m < M_; ++m) acc[m] = 0.f;
    for (int dq = 0; dq < D_ / 4; ++dq) {
        const float4 wv = wrow[dq];
#pragma unroll
        for (int m = 0; m < M_; ++m) {
            const float4 xv = xn[m * (D_ / 4) + dq];   // wave-uniform
            acc[m] += wv.x * xv.x + wv.y * xv.y + wv.z * xv.z + wv.w * xv.w;
        }
    }
    const float rs = 0.05103103630798287f;  // 1/sqrt(384)
    const float b = bq[c];
    float* qout = qs + ((size_t)n * C_ + c) * M_;
#pragma unroll
    for (int m = 0; m < M_; ++m) qout[m] = (acc[m] + b) * rs;
}

// ---------------------------------------------------------------------------
// K24: FUSED scores+exp+fusion. lf is read from HBM exactly ONCE; e never
// hits global. Block = (n, lg): 512 thr (8 waves), owns 6-7 l-tiles of 64.
// Per tile:
//   phase A: scores[m][l-lane] — c split 8 ways across waves from the
//            prefetch REGISTERS (val[48]); partials tree-reduced via LDS;
//            exp -> e_lds; S[m] accumulated (softmax denom, no max needed:
//            scores ~ N(0,1), fp32-safe).
//   phase B: accB[4m][12c] += e[m][l] * lf_lds[c][l] (K4's proven XOR-swizzle
//            layout: per-wave reads = 8 distinct quads broadcast, conflict-free).
// accB persists across tiles; merged across the 4 jg l-slices once at the end.
// Cross-lg partials (8 per n) reduced by K4b. LDS 147.7 KB -> 1 block/CU;
// grid 512 = 2 rounds/CU. Register prefetch of tile t+1 overlaps phase B.
// ---------------------------------------------------------------------------
__global__ __launch_bounds__(512) void k24_fused(const float* __restrict__ lf,
                                                 const float* __restrict__ qs,
                                                 float* __restrict__ fusionP,
                                                 float* __restrict__ Sp) {
    const int n  = blockIdx.x;
    const int lg = blockIdx.y;          // 0..7
    const int u  = threadIdx.x;         // 0..511
    const int lane = u & 63;
    const int wv   = u >> 6;            // 0..7

    const int t0 = (lg == 0) ? 0 : (6 * lg + 1);
    const int nt = (lg == 0) ? 7 : 6;   // 7 + 6*7 = 49 tiles total

    __shared__ float lf_lds[12][64][36];   // [chunk][l][c^swz] 110.6 KB
    __shared__ float e_lds[16][68];        // [m][l], stride 68: 2-way = free
    __shared__ float red[8][16][64];       // [wave][m][l] phase-A partials 32 KB

    // phase-B roles: 4 jg (16 l) x 32 cg (12 c as 3 stride-128 quads) x 4 mg (4 m)
    const int jg = u >> 7;
    const int cg = ((u >> 6) & 1) * 16 + ((u >> 2) & 15);  // 0..31
    const int mg = u & 3;
    const int swz_w = 4 * ((lane >> 3) & 7);

    const float* __restrict__ lfb = lf + (size_t)n * C_ * L_;
    const float* __restrict__ qn  = qs + (size_t)n * C_ * M_;

    float accB[4][12];
#pragma unroll
    for (int a = 0; a < 4; ++a)
#pragma unroll
        for (int b = 0; b < 12; ++b) accB[a][b] = 0.f;

    float val[48];
    {   // prologue: prefetch tile t0 (thread's 48 c-rows, coalesced in lane=l)
        const int l0 = t0 * 64 + lane;
#pragma unroll
        for (int ch = 0; ch < 12; ++ch)
#pragma unroll
            for (int i = 0; i < 4; ++i)
                val[ch * 4 + i] = lfb[(size_t)(ch * 32 + wv * 4 + i) * L_ + l0];
    }
    float SaccA = 0.f, SaccB = 0.f;

    for (int it = 0; it < nt; ++it) {
        // ---- phase A: per-wave partial scores over this wave's 48 c's ----
        float accA[16];
#pragma unroll
        for (int m = 0; m < 16; ++m) accA[m] = 0.f;
#pragma unroll
        for (int ch = 0; ch < 12; ++ch) {
#pragma unroll
            for (int i = 0; i < 4; ++i) {
                const int c = ch * 32 + wv * 4 + i;      // wave-uniform
                const float v = val[ch * 4 + i];
                const float4* __restrict__ qv = (const float4*)(qn + (size_t)c * M_);
                const float4 q0 = qv[0], q1 = qv[1], q2 = qv[2], q3 = qv[3];
                accA[0]  += q0.x * v; accA[1]  += q0.y * v; accA[2]  += q0.z * v; accA[3]  += q0.w * v;
                accA[4]  += q1.x * v; accA[5]  += q1.y * v; accA[6]  += q1.z * v; accA[7]  += q1.w * v;
                accA[8]  += q2.x * v; accA[9]  += q2.y * v; accA[10] += q2.z * v; accA[11] += q2.w * v;
                accA[12] += q3.x * v; accA[13] += q3.y * v; accA[14] += q3.z * v; accA[15] += q3.w * v;
            }
        }
        // ---- stage val -> LDS (K4's swizzle; prev phase B done = last barrier)
#pragma unroll
        for (int ch = 0; ch < 12; ++ch)
            *(float4*)&lf_lds[ch][lane][(wv * 4) ^ swz_w] =
                make_float4(val[ch * 4 + 0], val[ch * 4 + 1], val[ch * 4 + 2], val[ch * 4 + 3]);
#pragma unroll
        for (int m = 0; m < 16; ++m) red[wv][m][lane] = accA[m];
        __syncthreads();
        // ---- reduce partials, exp, denominators (wave wv owns m=wv, m=8+wv)
        {
            float s1 = 0.f, s2 = 0.f;
#pragma unroll
            for (int w = 0; w < 8; ++w) s1 += red[w][wv][lane];
#pragma unroll
            for (int w = 0; w < 8; ++w) s2 += red[w][8 + wv][lane];
            const float e1 = __expf(s1), e2 = __expf(s2);
            e_lds[wv][lane]     = e1;
            e_lds[8 + wv][lane] = e2;
            SaccA += e1;
            SaccB += e2;
        }
        // ---- prefetch tile t+1 (in flight across phase B ~3K cycles)
        if (it + 1 < nt) {
            const int l0 = (t0 + it + 1) * 64 + lane;
#pragma unroll
            for (int ch = 0; ch < 12; ++ch)
#pragma unroll
                for (int i = 0; i < 4; ++i)
                    val[ch * 4 + i] = lfb[(size_t)(ch * 32 + wv * 4 + i) * L_ + l0];
        }
        __syncthreads();
        // ---- phase B: accB += e * lf over this jg's 16 l's ----
#pragma unroll
        for (int jj = 0; jj < 16; ++jj) {
            const int j = jg * 16 + jj;
            const int swzj = 4 * (((jg << 1) + (jj >> 3)) & 7);
            float es[4];
#pragma unroll
            for (int mi = 0; mi < 4; ++mi) es[mi] = e_lds[mg * 4 + mi][j];
#pragma unroll
            for (int qi = 0; qi < 3; ++qi) {
                const float4 lv = *(const float4*)&lf_lds[(cg >> 3) + 4 * qi][j][(4 * (cg & 7)) ^ swzj];
#pragma unroll
                for (int mi = 0; mi < 4; ++mi) {
                    accB[mi][qi * 4 + 0] += es[mi] * lv.x;
                    accB[mi][qi * 4 + 1] += es[mi] * lv.y;
                    accB[mi][qi * 4 + 2] += es[mi] * lv.z;
                    accB[mi][qi * 4 + 3] += es[mi] * lv.w;
                }
            }
        }
        __syncthreads();   // phase B done; next stage may overwrite LDS
    }

    // ---- merge accB across the 4 jg l-slices (alias lf_lds: 98 KB <= 110 KB)
    float* part = &lf_lds[0][0][0];
#pragma unroll
    for (int mi = 0; mi < 4; ++mi)
#pragma unroll
        for (int qi = 0; qi < 3; ++qi) {
            const int m = mg * 4 + mi;
            const int cb = 4 * cg + 128 * qi;
            *(float4*)&part[(jg * 16 + m) * 384 + cb] =
                make_float4(accB[mi][qi * 4 + 0], accB[mi][qi * 4 + 1],
                            accB[mi][qi * 4 + 2], accB[mi][qi * 4 + 3]);
        }
    __syncthreads();
    float* __restrict__ fout = fusionP + (size_t)(n * G_ + lg) * M_ * C_;
#pragma unroll
    for (int k = 0; k < 12; ++k) {
        const int o = u + 512 * k;        // 6144 outputs
        const int m = o / 384;
        const int c = o % 384;
        const float s = part[(0 * 16 + m) * 384 + c] + part[(1 * 16 + m) * 384 + c] +
                        part[(2 * 16 + m) * 384 + c] + part[(3 * 16 + m) * 384 + c];
        fout[o] = s;
    }
    // ---- Sp[n][lg][m]: butterfly lane-sums (wave wv owns m=wv, 8+wv)
    float sa = SaccA, sb = SaccB;
#pragma unroll
    for (int o = 32; o > 0; o >>= 1) { sa += __shfl_xor(sa, o, 64); sb += __shfl_xor(sb, o, 64); }
    if (lane == 0) {
        float* spn = Sp + (size_t)(n * G_ + lg) * M_;
        spn[wv]     = sa;
        spn[8 + wv] = sb;
    }
}

// ---------------------------------------------------------------------------
// K4b: fusionP[n][0][m][c] += sum_{p>=1} fusionP[n][p][m][c]  (8 partials)
// ---------------------------------------------------------------------------
__global__ __launch_bounds__(256) void k4b_reduce(float* __restrict__ fusionP) {
    const int i = blockIdx.x * 256 + threadIdx.x;   // 1536*256 = 393216 exact
    const int n = i / (M_ * C_);
    const int mc = i % (M_ * C_);
    float* p = fusionP + (size_t)n * G_ * M_ * C_ + mc;
    float v = p[0];
#pragma unroll
    for (int s2 = 1; s2 < G_; ++s2) v += p[s2 * M_ * C_];
    p[0] = v;
}

// ---------------------------------------------------------------------------
// K5: out[n][m][d] = (sum_c fusion[n][m][c]*Wu[d][c]) / S[n][m] + bu[d] + x
// S[n][m] = sum over 8 lg partials of Sp. Normalization commutes through Wu.
// ---------------------------------------------------------------------------
__global__ __launch_bounds__(128) void k5_out(const float* __restrict__ fusionP,
                                              const float* __restrict__ Sp,
                                              const float* __restrict__ Wu,
                                              const float* __restrict__ bu,
                                              const float* __restrict__ x,
                                              float* __restrict__ out) {
    const int n = blockIdx.x;
    const int d = blockIdx.y * 128 + threadIdx.x;   // 3*128 = 384 exact
    float S[M_];
#pragma unroll
    for (int m = 0; m < M_; ++m) S[m] = 0.f;
    const float* __restrict__ spn = Sp + (size_t)n * G_ * M_;
#pragma unroll
    for (int s = 0; s < G_; ++s) {
        const float4* __restrict__ sp4 = (const float4*)(spn + s * M_);
        const float4 a = sp4[0], b2 = sp4[1], c2 = sp4[2], d2 = sp4[3];
        S[0]  += a.x;  S[1]  += a.y;  S[2]  += a.z;  S[3]  += a.w;
        S[4]  += b2.x; S[5]  += b2.y; S[6]  += b2.z; S[7]  += b2.w;
        S[8]  += c2.x; S[9]  += c2.y; S[10] += c2.z; S[11] += c2.w;
        S[12] += d2.x; S[13] += d2.y; S[14] += d2.z; S[15] += d2.w;
    }
    float inv[M_];
#pragma unroll
    for (int m = 0; m < M_; ++m) inv[m] = 1.0f / S[m];

    const float4* __restrict__ wrow = (const float4*)(Wu + (size_t)d * C_);
    const float4* __restrict__ fn   = (const float4*)(fusionP + (size_t)n * G_ * M_ * C_);
    float acc[M_];
#pragma unroll
    for (int m = 0; m < M_; ++m) acc[m] = 0.f;
    for (int cq = 0; cq < C_ / 4; ++cq) {
        const float4 wv = wrow[cq];
#pragma unroll
        for (int m = 0; m < M_; ++m) {
            const float4 fv = fn[m * (C_ / 4) + cq];   // wave-uniform
            acc[m] += wv.x * fv.x + wv.y * fv.y + wv.z * fv.z + wv.w * fv.w;
        }
    }
    const float b = bu[d];
#pragma unroll
    for (int m = 0; m < M_; ++m) {
        const size_t o = ((size_t)n * M_ + m) * D_ + d;
        out[o] = acc[m] * inv[m] + b + x[o];
    }
}

// ---------------------------------------------------------------------------
extern "C" void kernel_launch(void* const* d_in, const int* in_sizes, int n_in,
                              void* d_out, int out_size, void* d_ws, size_t ws_size,
                              hipStream_t stream) {
    const float* lf = (const float*)d_in[0];   // [64,384,56,56]
    const float* x  = (const float*)d_in[1];   // [64,16,384]
    const float* Wq = (const float*)d_in[2];   // [384,384]
    const float* bq = (const float*)d_in[3];   // [384]
    const float* Wu = (const float*)d_in[4];   // [384,384]
    const float* bu = (const float*)d_in[5];   // [384]
    float* out = (float*)d_out;

    float* ws      = (float*)d_ws;
    float* qs      = ws;                        // [64][384][16]    = 393216 f
    float* fusionP = qs + 393216;               // [64][8][16][384] = 3145728 f
    float* Sp      = fusionP + 3145728;         // [64][8][16]      = 8192 f
                                                // total 14.2 MB of ws

    k1_qproj <<<dim3(64, 3), 128, 0, stream>>>(x, Wq, bq, qs);
    k24_fused<<<dim3(64, G_), 512, 0, stream>>>(lf, qs, fusionP, Sp);
    k4b_reduce<<<1536, 256, 0, stream>>>(fusionP);
    k5_out   <<<dim3(64, 3), 128, 0, stream>>>(fusionP, Sp, Wu, bu, x, out);
}